// Round 2
// baseline (4741.436 us; speedup 1.0000x reference)
//
#include <hip/hip_runtime.h>
#include <math.h>

#define B 128
#define S 512
#define E 128
#define R 256
#define G4 1024  // 4*R

// ---- workspace layout (float offsets) ----
// HS: [S+1][R/4][B][4]  (slot 0 = h_{-1} = zeros; step t reads slot t, writes t+1)
static const size_t HS_FLOATS = 513ull * (R / 4) * (B * 4);          // 16,809,984
static const size_t X4_OFF    = HS_FLOATS;                            // X: [S][E/4][B][4]
static const size_t WUT_OFF   = X4_OFF + (size_t)S * (E / 4) * (B * 4); // WUt: [G4][384]
static const size_t SYNC_OFF  = WUT_OFF + (size_t)G4 * 384;           // 1024 ints of sync space
static const size_t WS_FLOATS = SYNC_OFF + 1024;                      // ~102.4 MB total

// output: probs [B][S][9] then h_last [B][R] then c_last [B][R]
#define HOUT_OFF 589824
#define COUT_OFF 622592

__global__ void zero_state(float* __restrict__ HS, int* __restrict__ sync) {
    int i = blockIdx.x * 1024 + threadIdx.x;   // 32 blocks * 1024
    if (i < 32768) HS[i] = 0.f;                // HS slot 0
    if (i < 1024) sync[i] = 0;                 // barrier counters/flags
}

// X4[t][e4][b] = embed[idx[b][t]][e4]
__global__ void gather_x(const int* __restrict__ idx, const float* __restrict__ embed,
                         float4* __restrict__ X4) {
    int t    = blockIdx.x;
    int tid  = threadIdx.x;          // 256
    int b    = tid & 127;
    int half = tid >> 7;
    int row  = idx[(size_t)b * S + t];
    const float4* er = (const float4*)embed + (size_t)row * (E / 4);
    size_t xbase = (size_t)t * (E / 4) * B + b;
#pragma unroll
    for (int kk = 0; kk < 16; ++kk) {
        int e4 = half * 16 + kk;
        X4[xbase + (size_t)e4 * B] = er[e4];
    }
}

// WUt[j][s] : s<128 -> W[s][j], else U[s-128][j]
__global__ void make_wut(const float* __restrict__ W, const float* __restrict__ U,
                         float* __restrict__ WUt) {
    int j = blockIdx.x;
    int s = threadIdx.x;             // 384
    float v = (s < E) ? W[(size_t)s * G4 + j] : U[(size_t)(s - E) * G4 + j];
    WUt[(size_t)j * 384 + s] = v;
}

__device__ __forceinline__ float sigmoidf_(float x) { return 1.f / (1.f + __expf(-x)); }

// Persistent LSTM: 256 wgs x 512 threads. wg w: rpair=w>>1, bg=w&1.
// waves: wid 0..7 -> rl=wid>>2 (unit within pair), k=wid&3 (K-split quarter of 384 terms)
// k0: x e4 [0,24) ; k1: x e4 [24,32) + h r4 [0,16) ; k2: h r4 [16,40) ; k3: h r4 [40,64)
__launch_bounds__(512, 2)
__global__ void lstm_persist(const float4* __restrict__ X4, const float* __restrict__ WUt,
                             const float* __restrict__ bias, float* __restrict__ HS,
                             float* __restrict__ out, int* __restrict__ sync) {
    const int tid  = threadIdx.x;
    const int lane = tid & 63;
    const int wid  = __builtin_amdgcn_readfirstlane((int)(tid >> 6));
    const int k    = wid & 3;
    const int rl   = wid >> 2;
    const int w    = blockIdx.x;
    const int rpair = w >> 1;
    const int bg    = w & 1;
    const int r     = rpair * 2 + rl;
    const int b     = bg * 64 + lane;
    const int xg    = w & 7;          // XCD-round-robin group for L1 barrier

    __shared__ float partial[2][3][4][64];

    const float* wu0 = WUt + (size_t)(0 * R + r) * 384;
    const float* wu1 = WUt + (size_t)(1 * R + r) * 384;
    const float* wu2 = WUt + (size_t)(2 * R + r) * 384;
    const float* wu3 = WUt + (size_t)(3 * R + r) * 384;

    int* cnt1 = sync + xg * 64;
    int* flg1 = sync + 512 + xg * 64;
    int* cntr = sync + 1016;
    int* flgr = sync + 1020;

    float c = 0.f;

    for (int t = 0; t < S; ++t) {
        float a0, a1, a2, a3;
        if (k == 0) { a0 = bias[r]; a1 = bias[R + r]; a2 = bias[2 * R + r]; a3 = bias[3 * R + r]; }
        else        { a0 = a1 = a2 = a3 = 0.f; }

        const float4* xp = X4 + (size_t)t * (E / 4) * B;           // + e4*B + b
        const float4* hp = (const float4*)HS + (size_t)t * (R / 4) * B;  // + r4*B + b

#define MACX(E0, E1)                                                                   \
        _Pragma("unroll")                                                              \
        for (int m = (E0); m < (E1); ++m) {                                            \
            float4 v = xp[(size_t)m * B + b];                                          \
            int s = m * 4;                                                             \
            a0 += wu0[s] * v.x; a0 += wu0[s+1] * v.y; a0 += wu0[s+2] * v.z; a0 += wu0[s+3] * v.w; \
            a1 += wu1[s] * v.x; a1 += wu1[s+1] * v.y; a1 += wu1[s+2] * v.z; a1 += wu1[s+3] * v.w; \
            a2 += wu2[s] * v.x; a2 += wu2[s+1] * v.y; a2 += wu2[s+2] * v.z; a2 += wu2[s+3] * v.w; \
            a3 += wu3[s] * v.x; a3 += wu3[s+1] * v.y; a3 += wu3[s+2] * v.z; a3 += wu3[s+3] * v.w; \
        }
#define MACH(R0, R1)                                                                   \
        _Pragma("unroll")                                                              \
        for (int m = (R0); m < (R1); ++m) {                                            \
            float4 v = hp[(size_t)m * B + b];                                          \
            int s = E + m * 4;                                                         \
            a0 += wu0[s] * v.x; a0 += wu0[s+1] * v.y; a0 += wu0[s+2] * v.z; a0 += wu0[s+3] * v.w; \
            a1 += wu1[s] * v.x; a1 += wu1[s+1] * v.y; a1 += wu1[s+2] * v.z; a1 += wu1[s+3] * v.w; \
            a2 += wu2[s] * v.x; a2 += wu2[s+1] * v.y; a2 += wu2[s+2] * v.z; a2 += wu2[s+3] * v.w; \
            a3 += wu3[s] * v.x; a3 += wu3[s+1] * v.y; a3 += wu3[s+2] * v.z; a3 += wu3[s+3] * v.w; \
        }

        if (k == 0)      { MACX(0, 24) }
        else if (k == 1) { MACX(24, 32) MACH(0, 16) }
        else if (k == 2) { MACH(16, 40) }
        else             { MACH(40, 64) }
#undef MACX
#undef MACH

        if (k != 0) {
            partial[rl][k - 1][0][lane] = a0;
            partial[rl][k - 1][1][lane] = a1;
            partial[rl][k - 1][2][lane] = a2;
            partial[rl][k - 1][3][lane] = a3;
        }
        __syncthreads();

        if (k == 0) {
#pragma unroll
            for (int kk = 0; kk < 3; ++kk) {
                a0 += partial[rl][kk][0][lane];
                a1 += partial[rl][kk][1][lane];
                a2 += partial[rl][kk][2][lane];
                a3 += partial[rl][kk][3][lane];
            }
            float ig = sigmoidf_(a0);
            float fg = sigmoidf_(a1);
            float gg = tanhf(a2);
            float og = sigmoidf_(a3);
            c = fg * c + ig * gg;
            float h = og * tanhf(c);
            // coherent (L2-bypassing) store so other XCDs' normal loads see it via L3
            float* haddr = HS + ((size_t)(t + 1) * (R / 4) + (r >> 2)) * (B * 4) + (size_t)b * 4 + (r & 3);
            asm volatile("global_store_dword %0, %1, off sc0 sc1" :: "v"(haddr), "v"(h) : "memory");
            if (t == S - 1) {
                out[HOUT_OFF + (size_t)b * R + r] = h;
                out[COUT_OFF + (size_t)b * R + r] = c;
            }
        }
        asm volatile("s_waitcnt vmcnt(0)" ::: "memory");  // stores reached coherent point
        __syncthreads();

        if (t < S - 1) {
            if (tid == 0) {
                int epoch = t + 1;
                int a = __hip_atomic_fetch_add(cnt1, 1, __ATOMIC_ACQ_REL, __HIP_MEMORY_SCOPE_AGENT);
                if (a == 31) {                       // last of this XCD-group
                    __hip_atomic_store(cnt1, 0, __ATOMIC_RELAXED, __HIP_MEMORY_SCOPE_AGENT);
                    int rr = __hip_atomic_fetch_add(cntr, 1, __ATOMIC_ACQ_REL, __HIP_MEMORY_SCOPE_AGENT);
                    if (rr == 7) {                   // last group
                        __hip_atomic_store(cntr, 0, __ATOMIC_RELAXED, __HIP_MEMORY_SCOPE_AGENT);
                        __hip_atomic_store(flgr, epoch, __ATOMIC_RELEASE, __HIP_MEMORY_SCOPE_AGENT);
                    } else {
                        int it = 0;
                        while (__hip_atomic_load(flgr, __ATOMIC_RELAXED, __HIP_MEMORY_SCOPE_AGENT) < epoch
                               && ++it < (1 << 20)) __builtin_amdgcn_s_sleep(2);
                    }
                    __hip_atomic_store(flg1, epoch, __ATOMIC_RELEASE, __HIP_MEMORY_SCOPE_AGENT);
                } else {
                    int it = 0;
                    while (__hip_atomic_load(flg1, __ATOMIC_RELAXED, __HIP_MEMORY_SCOPE_AGENT) < epoch
                           && ++it < (1 << 20)) __builtin_amdgcn_s_sleep(2);
                }
            }
            __syncthreads();
        }
    }
}

// probs[b][t][c] = softmax(h_t @ Wout + bout).  grid = dim3(S, 2), block = 64.
__global__ void out_probs(const float* __restrict__ HS, const float* __restrict__ Wout,
                          const float* __restrict__ bout, float* __restrict__ out) {
    int t    = blockIdx.x;
    int bg   = blockIdx.y;
    int lane = threadIdx.x;          // 64
    int b    = bg * 64 + lane;
    float acc[9];
#pragma unroll
    for (int c = 0; c < 9; ++c) acc[c] = bout[c];
    const float4* hp = (const float4*)HS + (size_t)(t + 1) * (R / 4) * B + b;
#pragma unroll 4
    for (int r4 = 0; r4 < R / 4; ++r4) {
        float4 hv = hp[(size_t)r4 * B];
        int r = r4 * 4;
#pragma unroll
        for (int c = 0; c < 9; ++c) {
            acc[c] += hv.x * Wout[(size_t)(r + 0) * 9 + c];
            acc[c] += hv.y * Wout[(size_t)(r + 1) * 9 + c];
            acc[c] += hv.z * Wout[(size_t)(r + 2) * 9 + c];
            acc[c] += hv.w * Wout[(size_t)(r + 3) * 9 + c];
        }
    }
    float m = acc[0];
#pragma unroll
    for (int c = 1; c < 9; ++c) m = fmaxf(m, acc[c]);
    float e[9];
    float sum = 0.f;
#pragma unroll
    for (int c = 0; c < 9; ++c) { e[c] = expf(acc[c] - m); sum += e[c]; }
    float inv = 1.f / sum;
#pragma unroll
    for (int c = 0; c < 9; ++c) out[((size_t)b * S + t) * 9 + c] = e[c] * inv;
}

extern "C" void kernel_launch(void* const* d_in, const int* in_sizes, int n_in,
                              void* d_out, int out_size, void* d_ws, size_t ws_size,
                              hipStream_t stream) {
    const int*   idx   = (const int*)d_in[0];
    const float* embed = (const float*)d_in[1];
    const float* W     = (const float*)d_in[2];
    const float* U     = (const float*)d_in[3];
    const float* bias  = (const float*)d_in[4];
    const float* Wout  = (const float*)d_in[5];
    const float* bout  = (const float*)d_in[6];
    float*       out   = (float*)d_out;
    float*       ws    = (float*)d_ws;

    if (ws_size < WS_FLOATS * sizeof(float)) return;  // workspace too small: fail loudly

    float*  HS   = ws;
    float4* X4   = (float4*)(ws + X4_OFF);
    float*  WUt  = ws + WUT_OFF;
    int*    sync = (int*)(ws + SYNC_OFF);

    zero_state<<<32, 1024, 0, stream>>>(HS, sync);
    gather_x<<<S, 256, 0, stream>>>(idx, embed, X4);
    make_wut<<<G4, 384, 0, stream>>>(W, U, WUt);
    lstm_persist<<<256, 512, 0, stream>>>(X4, WUt, bias, HS, out, sync);
    out_probs<<<dim3(S, 2), 64, 0, stream>>>(HS, Wout, bout, out);
}

// Round 4
// 4639.195 us; speedup vs baseline: 1.0220x; 1.0220x over previous
//
#include <hip/hip_runtime.h>
#include <math.h>

#define B 128
#define S 512
#define E 128
#define R 256

#define NG 32      // groups (each owns 4 batch elements)
#define QW 8       // wgs per group
#define ELS 4      // batch elements per group
#define OUTS 128   // gate-outputs per wg = 4 gates x 32 units
#define UNITS 32

typedef float v2f __attribute__((ext_vector_type(2)));

// ---- workspace layout (float offsets) ----
static const size_t HX_OFF   = 0;                              // HX: [2][B][R] exchange buf (256 KB)
static const size_t XG_OFF   = HX_OFF + 2ull * B * R;          // Xg: [S][B][E]
static const size_t WUT_OFF  = XG_OFF + (size_t)S * B * E;     // WUt: [1024][384]
static const size_t SYNC_OFF = WUT_OFF + 1024ull * 384;        // 1024 ints
static const size_t WS_FLOATS = SYNC_OFF + 1024;               // ~35.4 MB

// output: probs [B][S][9] ; h_last [B][R] ; c_last [B][R]
#define HOUT_OFF 589824
#define COUT_OFF 622592

__global__ void zero_sync(int* __restrict__ sync) {
    sync[threadIdx.x] = 0;   // 1024 threads
}

// Xg[t][b][e] = embed[idx[b][t]][e]
__global__ void gather_x(const int* __restrict__ idx, const float* __restrict__ embed,
                         float* __restrict__ Xg) {
    int t    = blockIdx.x;
    int tid  = threadIdx.x;          // 256
    int b    = tid >> 1;
    int half = tid & 1;
    int row  = idx[(size_t)b * S + t];
    const float4* er = (const float4*)(embed + (size_t)row * E) + half * 16;
    float4* xw = (float4*)(Xg + ((size_t)t * B + b) * E) + half * 16;
#pragma unroll
    for (int k = 0; k < 16; ++k) xw[k] = er[k];
}

// WUt[j][s] : s<128 -> W[s][j], else U[s-128][j]
__global__ void make_wut(const float* __restrict__ W, const float* __restrict__ U,
                         float* __restrict__ WUt) {
    int j = blockIdx.x;
    int s = threadIdx.x;             // 384
    float v = (s < E) ? W[(size_t)s * 1024 + j] : U[(size_t)(s - E) * 1024 + j];
    WUt[(size_t)j * 384 + s] = v;
}

__device__ __forceinline__ float sigm(float x) { return 1.f / (1.f + __expf(-x)); }

// Persistent LSTM. grid = 256 (cooperative), block = 512.
// wg = g*8+q. Group g: batch elements [4g,4g+4). wg q: units [32q,32q+32), all 4 gates.
// Thread: tid = ks*128 + oi  (ks = wave>>1, wave-uniform; oi = 0..127 gate-output index)
__launch_bounds__(512, 2)
__global__ void lstm_persist(const float* __restrict__ Xg, const float* __restrict__ WUt,
                             const float* __restrict__ bias, const float* __restrict__ Wout,
                             const float* __restrict__ bout, float* __restrict__ out,
                             float* __restrict__ HX, int* __restrict__ sync) {
    __shared__ float act[ELS][E + R];          // [4][384]: x | h
    __shared__ float partial[4][ELS][OUTS];    // [ks][el][oi]
    __shared__ float woutT[9][260];            // transposed (260*4B = 65*16B -> rows 16B aligned)
    __shared__ float zrow[ELS][12];

    const int tid  = threadIdx.x;
    const int wg   = blockIdx.x;
    const int g    = wg >> 3;
    const int q    = wg & 7;
    const int lane = tid & 63;
    const int wv   = __builtin_amdgcn_readfirstlane(tid >> 6);
    const int ks   = wv >> 1;                      // 0..3 wave-uniform
    const int oi   = ((wv & 1) << 6) | lane;       // 0..127
    const int j    = (oi >> 5) * 256 + q * 32 + (oi & 31);  // weight row (gate*256 + unit)

    // ---- prologue: weights -> VGPRs ----
    float4 wx[8], wh[16];
    {
        const float4* wrow = (const float4*)(WUt + (size_t)j * 384);
#pragma unroll
        for (int p = 0; p < 8; ++p)  wx[p] = wrow[8 * ks + p];
#pragma unroll
        for (int p = 0; p < 16; ++p) wh[p] = wrow[32 + 16 * ks + p];
    }

    // finisher state (tid < 128): el = tid>>5, u = tid&31
    float bias_g0 = 0.f, bias_g1 = 0.f, bias_g2 = 0.f, bias_g3 = 0.f, creg = 0.f;
    if (tid < 128) {
        int u = tid & 31;
        bias_g0 = bias[0 * 256 + q * 32 + u];
        bias_g1 = bias[1 * 256 + q * 32 + u];
        bias_g2 = bias[2 * 256 + q * 32 + u];
        bias_g3 = bias[3 * 256 + q * 32 + u];
    }
    // probs constants (wave 0): lane -> el = lane>>4, c = lane&15
    float boutr = 0.f;
    if (wv == 0 && (lane & 15) < 9) boutr = bout[lane & 15];

    // Wout transpose into LDS
    for (int i = tid; i < 9 * 256; i += 512) {
        int c = i >> 8, r = i & 255;
        woutT[c][r] = Wout[(size_t)r * 9 + c];
    }
    // zero act h-part; load x_0 into act x-part
    for (int i = tid; i < ELS * (E + R); i += 512) ((float*)act)[i] = 0.f;
    __syncthreads();
    if (tid < 256) {
        int el = tid >> 6, e2 = (tid & 63) * 2;
        *(v2f*)&act[el][e2] = *(const v2f*)&Xg[((size_t)0 * B + g * 4 + el) * E + e2];
    }
    __syncthreads();

    int* cnt = sync + g * 32;
    int* flg = sync + g * 32 + 16;

    for (int t = 0; t < S; ++t) {
        // ---- MAC: z[oi] partial over chunk ks, all 4 els ----
        float ac0 = 0.f, ac1 = 0.f, ac2 = 0.f, ac3 = 0.f;
        {
            const int xo = 32 * ks;
#pragma unroll
            for (int p = 0; p < 8; ++p) {
                float4 w  = wx[p];
                float4 a0 = *(const float4*)&act[0][xo + 4 * p];
                float4 a1 = *(const float4*)&act[1][xo + 4 * p];
                float4 a2 = *(const float4*)&act[2][xo + 4 * p];
                float4 a3 = *(const float4*)&act[3][xo + 4 * p];
                ac0 += w.x * a0.x + w.y * a0.y + w.z * a0.z + w.w * a0.w;
                ac1 += w.x * a1.x + w.y * a1.y + w.z * a1.z + w.w * a1.w;
                ac2 += w.x * a2.x + w.y * a2.y + w.z * a2.z + w.w * a2.w;
                ac3 += w.x * a3.x + w.y * a3.y + w.z * a3.z + w.w * a3.w;
            }
            const int ho = E + 64 * ks;
#pragma unroll
            for (int p = 0; p < 16; ++p) {
                float4 w  = wh[p];
                float4 a0 = *(const float4*)&act[0][ho + 4 * p];
                float4 a1 = *(const float4*)&act[1][ho + 4 * p];
                float4 a2 = *(const float4*)&act[2][ho + 4 * p];
                float4 a3 = *(const float4*)&act[3][ho + 4 * p];
                ac0 += w.x * a0.x + w.y * a0.y + w.z * a0.z + w.w * a0.w;
                ac1 += w.x * a1.x + w.y * a1.y + w.z * a1.z + w.w * a1.w;
                ac2 += w.x * a2.x + w.y * a2.y + w.z * a2.z + w.w * a2.w;
                ac3 += w.x * a3.x + w.y * a3.y + w.z * a3.z + w.w * a3.w;
            }
        }
        partial[ks][0][oi] = ac0;
        partial[ks][1][oi] = ac1;
        partial[ks][2][oi] = ac2;
        partial[ks][3][oi] = ac3;
        __syncthreads();  // #1

        // ---- finish: gates, c/h update, coherent h store ----
        if (tid < 128) {
            int el = tid >> 5, u = tid & 31;
            float z0 = bias_g0, z1 = bias_g1, z2 = bias_g2, z3 = bias_g3;
#pragma unroll
            for (int kk = 0; kk < 4; ++kk) {
                z0 += partial[kk][el][0 * 32 + u];
                z1 += partial[kk][el][1 * 32 + u];
                z2 += partial[kk][el][2 * 32 + u];
                z3 += partial[kk][el][3 * 32 + u];
            }
            float ig = sigm(z0), fg = sigm(z1), gv = tanhf(z2), og = sigm(z3);
            creg = fg * creg + ig * gv;
            float h = og * tanhf(creg);
            float* haddr = HX + ((size_t)(t & 1) * B + g * 4 + el) * R + q * 32 + u;
            asm volatile("global_store_dword %0, %1, off sc0 sc1" :: "v"(haddr), "v"(h) : "memory");
            if (t == S - 1) {
                out[HOUT_OFF + (size_t)(g * 4 + el) * R + q * 32 + u] = h;
                out[COUT_OFF + (size_t)(g * 4 + el) * R + q * 32 + u] = creg;
            }
        }
        // prefetch x_{t+1} into regs (normal cached loads)
        v2f xpre;
        const bool do_x = (tid < 256) && (t < S - 1);
        if (do_x) {
            int el = tid >> 6, e2 = (tid & 63) * 2;
            xpre = *(const v2f*)&Xg[((size_t)(t + 1) * B + g * 4 + el) * E + e2];
        }
        asm volatile("s_waitcnt vmcnt(0)" ::: "memory");
        __syncthreads();  // #2

        // ---- group barrier (8 wgs) ----
        if (tid == 0) {
            int epoch = t + 1;
            int old = __hip_atomic_fetch_add(cnt, 1, __ATOMIC_ACQ_REL, __HIP_MEMORY_SCOPE_AGENT);
            if (old == QW - 1) {
                __hip_atomic_store(cnt, 0, __ATOMIC_RELAXED, __HIP_MEMORY_SCOPE_AGENT);
                __hip_atomic_store(flg, epoch, __ATOMIC_RELEASE, __HIP_MEMORY_SCOPE_AGENT);
            } else {
                int it = 0;
                while (__hip_atomic_load(flg, __ATOMIC_RELAXED, __HIP_MEMORY_SCOPE_AGENT) < epoch
                       && ++it < (1 << 16)) {}
            }
        }
        __syncthreads();  // #3

        // ---- pull h_t (coherent) + write act for next step ----
        {
            int el = tid >> 7, r2 = (tid & 127) * 2;
            const float* hsrc = HX + ((size_t)(t & 1) * B + g * 4 + el) * R + r2;
            v2f hv;
            asm volatile("global_load_dwordx2 %0, %1, off sc0 sc1" : "=v"(hv) : "v"(hsrc) : "memory");
            asm volatile("s_waitcnt vmcnt(0)" ::: "memory");
            *(v2f*)&act[el][E + r2] = hv;
        }
        if (do_x) {
            int el = tid >> 6, e2 = (tid & 63) * 2;
            *(v2f*)&act[el][e2] = xpre;
        }
        __syncthreads();  // #4

        // ---- probs for step t (rotating wg, wave 0 only; act h-part == h_t) ----
        if (q == (t & 7) && wv == 0) {
            int el = lane >> 4, c = lane & 15;
            float z = boutr;
            if (c < 9) {
#pragma unroll 16
                for (int p = 0; p < 64; ++p) {
                    float4 w = *(const float4*)&woutT[c][4 * p];
                    float4 a = *(const float4*)&act[el][E + 4 * p];
                    z += w.x * a.x + w.y * a.y + w.z * a.z + w.w * a.w;
                }
                zrow[el][c] = z;
            }
            asm volatile("s_waitcnt lgkmcnt(0)" ::: "memory");
            if (c < 9) {
                float m = zrow[el][0];
#pragma unroll
                for (int cc = 1; cc < 9; ++cc) m = fmaxf(m, zrow[el][cc]);
                float ssum = 0.f;
#pragma unroll
                for (int cc = 0; cc < 9; ++cc) ssum += __expf(zrow[el][cc] - m);
                out[((size_t)(g * 4 + el) * S + t) * 9 + c] = __expf(z - m) / ssum;
            }
        }
    }
}

extern "C" void kernel_launch(void* const* d_in, const int* in_sizes, int n_in,
                              void* d_out, int out_size, void* d_ws, size_t ws_size,
                              hipStream_t stream) {
    const int*   idx   = (const int*)d_in[0];
    const float* embed = (const float*)d_in[1];
    const float* W     = (const float*)d_in[2];
    const float* U     = (const float*)d_in[3];
    const float* bias  = (const float*)d_in[4];
    const float* Wout  = (const float*)d_in[5];
    const float* bout  = (const float*)d_in[6];
    float*       outp  = (float*)d_out;
    float*       ws    = (float*)d_ws;

    if (ws_size < WS_FLOATS * sizeof(float)) return;

    float* HX   = ws + HX_OFF;
    float* Xg   = ws + XG_OFF;
    float* WUt  = ws + WUT_OFF;
    int*   sy   = (int*)(ws + SYNC_OFF);

    zero_sync<<<1, 1024, 0, stream>>>(sy);
    gather_x<<<S, 256, 0, stream>>>(idx, embed, Xg);
    make_wut<<<1024, 384, 0, stream>>>(W, U, WUt);

    void* args[] = {&Xg, &WUt, &bias, &Wout, &bout, &outp, &HX, &sy};
    (void)hipLaunchCooperativeKernel((const void*)lstm_persist, dim3(256), dim3(512),
                                     args, 0, stream);
}